// Round 7
// baseline (205.505 us; speedup 1.0000x reference)
//
#include <hip/hip_runtime.h>
#include <math.h>

// Problem constants
#define NQ     25      // number of query images (= n_support)
#define NWAY   5
#define KSHOT  5
#define CC     640     // channels (k-dim of S gemm; 640 = 20*32)
#define HW     196     // 14*14
#define NSL    980     // NWAY*HW support locations
#define NSLP   992     // padded K for M-gemm (31*32)
#define RPQ    208     // padded row count per query (13*16)
#define MP     224     // padded M dim (7*32): row stride & K of squarings
#define MROWS  256     // allocated rows per M matrix (tile reads stay in-bounds)
#define GAMMA  20.0f
#define GAMMA2 10.0f
// Solve: (I-M)^-1 ~ (I+M)(I+M^2)(I+M^4) = sum_{k=0}^{7} M^k; ||M||_1 = 0.25
// -> truncation 0.25^8/0.75 ~ 2e-5, threshold 1.77e-2.

typedef __bf16 bf16;
typedef __attribute__((ext_vector_type(8))) __bf16 bf16x8;
typedef __attribute__((ext_vector_type(4))) float f32x4;

// ---------------------------------------------------------------------------
// K1: prototype mean + per-location L2 normalization -> TRANSPOSED bf16.
// ---------------------------------------------------------------------------
__global__ __launch_bounds__(256) void k_norm(const float* __restrict__ feat,
                                              bf16* __restrict__ qnbt,
                                              bf16* __restrict__ snbt) {
    const int by = blockIdx.y;
    const int lx = threadIdx.x & 15;
    const int cg = threadIdx.x >> 4;
    const int l  = blockIdx.x * 16 + lx;
    const bool act = (l < HW);
    const int c0 = cg * 40;
    __shared__ float pr[16][17];

    float xv[40];
    float ss = 0.f;
    if (by < NQ) {
        const float* f = feat + (size_t)(NQ + by) * CC * HW;
#pragma unroll
        for (int i = 0; i < 40; ++i) {
            float x = act ? f[(c0 + i) * HW + l] : 0.f;
            xv[i] = x; ss += x * x;
        }
    } else {
        const int s = by - NQ;
        const float* f = feat + (size_t)(NQ + s * KSHOT) * CC * HW;
        const size_t img = (size_t)CC * HW;
#pragma unroll
        for (int i = 0; i < 40; ++i) {
            float m = 0.f;
            if (act) {
                const float* p = f + (c0 + i) * HW + l;
                m = 0.2f * (p[0] + p[img] + p[2 * img] + p[3 * img] + p[4 * img]);
            }
            xv[i] = m; ss += m * m;
        }
    }
    pr[cg][lx] = ss;
    __syncthreads();
    if (cg == 0) {
        float a = 0.f;
#pragma unroll
        for (int k = 0; k < 16; ++k) a += pr[k][lx];
        pr[0][lx] = 1.f / (1e-16f + sqrtf(a));
    }
    __syncthreads();
    const float inv = pr[0][lx];
    if (act) {
        bf16* o = (by < NQ) ? (qnbt + ((size_t)by * RPQ + l) * CC)
                            : (snbt + ((size_t)(by - NQ) * HW + l) * CC);
#pragma unroll
        for (int i = 0; i < 40; ++i) o[c0 + i] = (bf16)(xv[i] * inv);
    }
}

// ---------------------------------------------------------------------------
// K2: S[q][m][j] = sum_c qnbt[q][m][c] * snbt[j][c]   via 16x16x32 bf16 MFMA.
// One wave per 64x64 tile (4x4 of 16x16). grid (16,4,25), 64 threads.
// ---------------------------------------------------------------------------
__global__ __launch_bounds__(64) void k_sgemm(const bf16* __restrict__ qnbt,
                                              const bf16* __restrict__ snbt,
                                              float* __restrict__ S) {
    const int q  = blockIdx.z;
    const int mt = blockIdx.y;
    const int nt = blockIdx.x;
    const int l  = threadIdx.x;
    const int lo = l & 15, hi = l >> 4;
    const bf16* Ap[4];
    const bf16* Bp[4];
#pragma unroll
    for (int mi = 0; mi < 4; ++mi)
        Ap[mi] = qnbt + ((size_t)q * RPQ + mt * 64 + mi * 16 + lo) * CC + hi * 8;
#pragma unroll
    for (int ni = 0; ni < 4; ++ni)
        Bp[ni] = snbt + ((size_t)(nt * 64 + ni * 16 + lo)) * CC + hi * 8;

    f32x4 acc[4][4] = {};
#pragma unroll 2
    for (int k0 = 0; k0 < CC; k0 += 32) {
        bf16x8 a[4], b[4];
#pragma unroll
        for (int mi = 0; mi < 4; ++mi) a[mi] = *reinterpret_cast<const bf16x8*>(Ap[mi] + k0);
#pragma unroll
        for (int ni = 0; ni < 4; ++ni) b[ni] = *reinterpret_cast<const bf16x8*>(Bp[ni] + k0);
#pragma unroll
        for (int mi = 0; mi < 4; ++mi)
#pragma unroll
            for (int ni = 0; ni < 4; ++ni)
                acc[mi][ni] = __builtin_amdgcn_mfma_f32_16x16x32_bf16(a[mi], b[ni], acc[mi][ni], 0, 0, 0);
    }

    float* Sq = S + (size_t)q * HW * NSL;
#pragma unroll
    for (int mi = 0; mi < 4; ++mi) {
#pragma unroll
        for (int ni = 0; ni < 4; ++ni) {
            const int j = nt * 64 + ni * 16 + lo;
            if (j >= NSL) continue;
#pragma unroll
            for (int r = 0; r < 4; ++r) {
                int m = mt * 64 + mi * 16 + hi * 4 + r;
                if (m < HW) Sq[(size_t)m * NSL + j] = acc[mi][ni][r];
            }
        }
    }
}

// ---------------------------------------------------------------------------
// K3a: Ts row softmax -> bf16 (stride NSLP, K-pads 0) + fused class row-sums
//      R[q][s][m].  One block per (q,m) row.
// ---------------------------------------------------------------------------
__global__ __launch_bounds__(256) void k_ts(const float* __restrict__ S,
                                            bf16* __restrict__ Ts,
                                            float* __restrict__ R) {
    const int qm = blockIdx.x;
    const int q = qm / HW, m = qm - q * HW;
    const float* row = S + (size_t)qm * NSL;
    bf16* orow = Ts + ((size_t)q * RPQ + m) * NSLP;
    const int t = threadIdx.x, lane = t & 63, wv = t >> 6;
    __shared__ float redm[4], reds[4], rred[NWAY][4];
    float x[4];
    float mx = -1e30f;
#pragma unroll
    for (int p = 0; p < 4; ++p) {
        int j = t + p * 256;
        x[p] = (j < NSL) ? row[j] : -1e30f;
        mx = fmaxf(mx, x[p]);
    }
    for (int d = 32; d; d >>= 1) mx = fmaxf(mx, __shfl_xor(mx, d));
    if (lane == 0) redm[wv] = mx;
    __syncthreads();
    mx = fmaxf(fmaxf(redm[0], redm[1]), fmaxf(redm[2], redm[3]));
    float e[4], sum = 0.f;
#pragma unroll
    for (int p = 0; p < 4; ++p) {
        e[p] = expf(GAMMA * (x[p] - mx));
        sum += e[p];
    }
    for (int d = 32; d; d >>= 1) sum += __shfl_xor(sum, d);
    if (lane == 0) reds[wv] = sum;
    __syncthreads();
    const float inv = 1.f / (reds[0] + reds[1] + reds[2] + reds[3]);
    float racc[NWAY];
#pragma unroll
    for (int s = 0; s < NWAY; ++s) racc[s] = 0.f;
#pragma unroll
    for (int p = 0; p < 4; ++p) {
        int j = t + p * 256;
        if (j < NSL) {
            float val = e[p] * inv;
            orow[j] = (bf16)val;
            int cls = j / HW;
#pragma unroll
            for (int s = 0; s < NWAY; ++s) racc[s] += (cls == s) ? val : 0.f;
        } else if (j < NSLP) {
            orow[j] = (bf16)0.f;
        }
    }
#pragma unroll
    for (int s = 0; s < NWAY; ++s) {
        float a = racc[s];
        for (int d = 32; d; d >>= 1) a += __shfl_xor(a, d);
        if (lane == 0) rred[s][wv] = a;
    }
    __syncthreads();
    if (t < NWAY)
        R[((size_t)q * NWAY + t) * HW + m] =
            rred[t][0] + rred[t][1] + rred[t][2] + rred[t][3];
}

// ---------------------------------------------------------------------------
// K3b: Tq column softmax -> bf16, K-pads 0. grid (16, 25).
// ---------------------------------------------------------------------------
__global__ __launch_bounds__(256) void k_tq(const float* __restrict__ S,
                                            bf16* __restrict__ Tq) {
    const int q  = blockIdx.y;
    const int tx = threadIdx.x & 63;
    const int tg = threadIdx.x >> 6;
    const int j  = blockIdx.x * 64 + tx;
    const int m0 = tg * 49;
    const float* base = S + (size_t)q * HW * NSL;
    bf16* ob = Tq + (size_t)q * RPQ * NSLP;
    __shared__ float rmax[4][64], rsum[4][64];
    float xv[49];
    float mx = -1e30f;
    if (j < NSL) {
#pragma unroll
        for (int i = 0; i < 49; ++i) {
            xv[i] = base[(m0 + i) * NSL + j];
            mx = fmaxf(mx, xv[i]);
        }
    }
    rmax[tg][tx] = mx;
    __syncthreads();
    mx = fmaxf(fmaxf(rmax[0][tx], rmax[1][tx]), fmaxf(rmax[2][tx], rmax[3][tx]));
    float sum = 0.f;
    if (j < NSL) {
#pragma unroll
        for (int i = 0; i < 49; ++i) {
            xv[i] = expf(GAMMA2 * (xv[i] - mx));
            sum += xv[i];
        }
    }
    rsum[tg][tx] = sum;
    __syncthreads();
    const float inv = 1.f / (rsum[0][tx] + rsum[1][tx] + rsum[2][tx] + rsum[3][tx]);
    if (j < NSL) {
#pragma unroll
        for (int i = 0; i < 49; ++i) ob[(size_t)(m0 + i) * NSLP + j] = (bf16)(xv[i] * inv);
    } else if (j < NSLP) {
#pragma unroll
        for (int i = 0; i < 49; ++i) ob[(size_t)(m0 + i) * NSLP + j] = (bf16)0.f;
    }
}

// ---------------------------------------------------------------------------
// K3c: rhs[qm] = 1 + 0.5 * rowsum(Tq[qm][:NSL]).  One block per (q,m) row.
// ---------------------------------------------------------------------------
__global__ __launch_bounds__(256) void k_rhs(const bf16* __restrict__ Tq,
                                             float* __restrict__ rhs) {
    const int qm = blockIdx.x;
    const int q = qm / HW, m = qm - q * HW;
    const bf16* row = Tq + ((size_t)q * RPQ + m) * NSLP;
    const int t = threadIdx.x, lane = t & 63, wv = t >> 6;
    __shared__ float red[4];
    float s = 0.f;
#pragma unroll
    for (int p = 0; p < 4; ++p) {
        int j = t + p * 256;
        if (j < NSL) s += (float)row[j];
    }
    for (int d = 32; d; d >>= 1) s += __shfl_xor(s, d);
    if (lane == 0) red[wv] = s;
    __syncthreads();
    if (t == 0) rhs[qm] = 1.f + 0.5f * (red[0] + red[1] + red[2] + red[3]);
}

// ---------------------------------------------------------------------------
// K4: M = 0.25 * Tq (196x992) * Ts^T (992x196) -> bf16 Mb AND MbT, 224-padded
// (pads written 0). grid (4 j, 4 i, 25 q), 64 threads.
// ---------------------------------------------------------------------------
__global__ __launch_bounds__(64) void k_mgemm(const bf16* __restrict__ Tq,
                                              const bf16* __restrict__ Ts,
                                              bf16* __restrict__ Mb,
                                              bf16* __restrict__ MbT) {
    const int q  = blockIdx.z;
    const int it = blockIdx.y;
    const int jt = blockIdx.x;
    const int l  = threadIdx.x;
    const int lo = l & 15, hi = l >> 4;
    const bf16* Ap[4];
    const bf16* Bp[4];
#pragma unroll
    for (int mi = 0; mi < 4; ++mi)
        Ap[mi] = Tq + ((size_t)q * RPQ + it * 64 + mi * 16 + lo) * NSLP + hi * 8;
#pragma unroll
    for (int ni = 0; ni < 4; ++ni)
        Bp[ni] = Ts + ((size_t)q * RPQ + jt * 64 + ni * 16 + lo) * NSLP + hi * 8;

    f32x4 acc[4][4] = {};
#pragma unroll 2
    for (int k0 = 0; k0 < NSLP; k0 += 32) {
        bf16x8 a[4], b[4];
#pragma unroll
        for (int mi = 0; mi < 4; ++mi) a[mi] = *reinterpret_cast<const bf16x8*>(Ap[mi] + k0);
#pragma unroll
        for (int ni = 0; ni < 4; ++ni) b[ni] = *reinterpret_cast<const bf16x8*>(Bp[ni] + k0);
#pragma unroll
        for (int mi = 0; mi < 4; ++mi)
#pragma unroll
            for (int ni = 0; ni < 4; ++ni)
                acc[mi][ni] = __builtin_amdgcn_mfma_f32_16x16x32_bf16(a[mi], b[ni], acc[mi][ni], 0, 0, 0);
    }

    bf16* Mq  = Mb  + (size_t)q * MROWS * MP;
    bf16* MqT = MbT + (size_t)q * MROWS * MP;
#pragma unroll
    for (int mi = 0; mi < 4; ++mi) {
#pragma unroll
        for (int ni = 0; ni < 4; ++ni) {
            const int j = jt * 64 + ni * 16 + lo;
            if (j >= MP) continue;
#pragma unroll
            for (int r = 0; r < 4; ++r) {
                int i = it * 64 + mi * 16 + hi * 4 + r;
                if (i >= MP) continue;
                bf16 val = (i < HW && j < HW) ? (bf16)(0.25f * acc[mi][ni][r]) : (bf16)0.f;
                Mq[(size_t)i * MP + j] = val;
                MqT[(size_t)j * MP + i] = val;
            }
        }
    }
}

// ---------------------------------------------------------------------------
// K5: batched squaring C = A*A (via A row-major x At row-major, NT form),
// bf16 MFMA, K=224 (pads zero).  Outputs C and Ct, pads written 0.
// grid (4 j, 4 i, 25 q), 64 threads.
// ---------------------------------------------------------------------------
__global__ __launch_bounds__(64) void k_msq(const bf16* __restrict__ A,
                                            const bf16* __restrict__ At,
                                            bf16* __restrict__ C,
                                            bf16* __restrict__ Ct) {
    const int q  = blockIdx.z;
    const int it = blockIdx.y;
    const int jt = blockIdx.x;
    const int l  = threadIdx.x;
    const int lo = l & 15, hi = l >> 4;
    const bf16* Ap[4];
    const bf16* Bp[4];
#pragma unroll
    for (int mi = 0; mi < 4; ++mi)
        Ap[mi] = A + (size_t)q * MROWS * MP + (size_t)(it * 64 + mi * 16 + lo) * MP + hi * 8;
#pragma unroll
    for (int ni = 0; ni < 4; ++ni)
        Bp[ni] = At + (size_t)q * MROWS * MP + (size_t)(jt * 64 + ni * 16 + lo) * MP + hi * 8;

    f32x4 acc[4][4] = {};
#pragma unroll
    for (int k0 = 0; k0 < MP; k0 += 32) {
        bf16x8 a[4], b[4];
#pragma unroll
        for (int mi = 0; mi < 4; ++mi) a[mi] = *reinterpret_cast<const bf16x8*>(Ap[mi] + k0);
#pragma unroll
        for (int ni = 0; ni < 4; ++ni) b[ni] = *reinterpret_cast<const bf16x8*>(Bp[ni] + k0);
#pragma unroll
        for (int mi = 0; mi < 4; ++mi)
#pragma unroll
            for (int ni = 0; ni < 4; ++ni)
                acc[mi][ni] = __builtin_amdgcn_mfma_f32_16x16x32_bf16(a[mi], b[ni], acc[mi][ni], 0, 0, 0);
    }

    bf16* Cq  = C  + (size_t)q * MROWS * MP;
    bf16* CqT = Ct + (size_t)q * MROWS * MP;
#pragma unroll
    for (int mi = 0; mi < 4; ++mi) {
#pragma unroll
        for (int ni = 0; ni < 4; ++ni) {
            const int j = jt * 64 + ni * 16 + lo;
            if (j >= MP) continue;
#pragma unroll
            for (int r = 0; r < 4; ++r) {
                int i = it * 64 + mi * 16 + hi * 4 + r;
                if (i >= MP) continue;
                bf16 val = (i < HW && j < HW) ? (bf16)acc[mi][ni][r] : (bf16)0.f;
                Cq[(size_t)i * MP + j] = val;
                CqT[(size_t)j * MP + i] = val;
            }
        }
    }
}

// ---------------------------------------------------------------------------
// K6: Rtot[q][s][m] = R[q][s][m] + sum_k R[q][s][k] * M[k][m]   (uses MbT)
// grid (4, 25), 256 threads.
// ---------------------------------------------------------------------------
__global__ __launch_bounds__(256) void k_rm(const bf16* __restrict__ MbT,
                                            const float* __restrict__ R,
                                            float* __restrict__ Rtot) {
    const int q = blockIdx.y, bx = blockIdx.x;
    const int t = threadIdx.x, lane = t & 63, wv = t >> 6;
    const float* Rq = R + (size_t)q * NWAY * HW;
    __shared__ float Rs[NWAY][HW];
    for (int i = t; i < NWAY * HW; i += 256) Rs[i / HW][i % HW] = Rq[i];
    __syncthreads();
    const bf16* Mq = MbT + (size_t)q * MROWS * MP;
    for (int m = bx * 49 + wv; m < bx * 49 + 49; m += 4) {
        const bf16* row = Mq + (size_t)m * MP;
        float a[NWAY] = {0.f, 0.f, 0.f, 0.f, 0.f};
        for (int k = lane; k < HW; k += 64) {
            float mv = (float)row[k];
#pragma unroll
            for (int s = 0; s < NWAY; ++s) a[s] += mv * Rs[s][k];
        }
#pragma unroll
        for (int s = 0; s < NWAY; ++s) {
            float v = a[s];
            for (int d = 32; d; d >>= 1) v += __shfl_xor(v, d);
            if (lane == 0) Rtot[((size_t)q * NWAY + s) * HW + m] = Rs[s][m] + v;
        }
    }
}

// ---------------------------------------------------------------------------
// K7: y[q] = x[q] + A[q] * x[q]   (A bf16 224-stride, x/y fp32[196])
// grid (4, 25), 256 threads.
// ---------------------------------------------------------------------------
__global__ __launch_bounds__(256) void k_mv(const bf16* __restrict__ A,
                                            const float* __restrict__ x,
                                            float* __restrict__ y) {
    const int q = blockIdx.y, bx = blockIdx.x;
    const int t = threadIdx.x, lane = t & 63, wv = t >> 6;
    __shared__ float xs[HW];
    const float* xq = x + (size_t)q * HW;
    if (t < HW) xs[t] = xq[t];
    __syncthreads();
    const bf16* Aq = A + (size_t)q * MROWS * MP;
    for (int r = bx * 49 + wv; r < bx * 49 + 49; r += 4) {
        const bf16* row = Aq + (size_t)r * MP;
        float a = 0.f;
        for (int c = lane; c < HW; c += 64) a += (float)row[c] * xs[c];
        for (int d = 32; d; d >>= 1) a += __shfl_xor(a, d);
        if (lane == 0) y[(size_t)q * HW + r] = xs[r] + a;
    }
}

// ---------------------------------------------------------------------------
// K8: out[q][s] = (Rtot[q][s] . v[q]) / sum_s'   grid 25 blocks, 320 threads.
// ---------------------------------------------------------------------------
__global__ __launch_bounds__(320) void k_out2(const float* __restrict__ Rtot,
                                              const float* __restrict__ v,
                                              float* __restrict__ out) {
    const int q = blockIdx.x;
    const int t = threadIdx.x, lane = t & 63, s = t >> 6;   // 5 waves
    __shared__ float cls[NWAY];
    const float* vq = v + (size_t)q * HW;
    const float* Rs = Rtot + ((size_t)q * NWAY + s) * HW;
    float a = 0.f;
    for (int m = lane; m < HW; m += 64) a += Rs[m] * vq[m];
    for (int d = 32; d; d >>= 1) a += __shfl_xor(a, d);
    if (lane == 0) cls[s] = a;
    __syncthreads();
    if (t == 0) {
        float tot = cls[0] + cls[1] + cls[2] + cls[3] + cls[4];
        float invt = 1.f / tot;
        for (int i = 0; i < NWAY; ++i) out[q * NWAY + i] = cls[i] * invt;
    }
}

// ---------------------------------------------------------------------------
extern "C" void kernel_launch(void* const* d_in, const int* in_sizes, int n_in,
                              void* d_out, int out_size, void* d_ws, size_t ws_size,
                              hipStream_t stream) {
    const float* feat = (const float*)d_in[0];
    float* out = (float*)d_out;
    char* w = (char*)d_ws;

    const size_t MSZ = (size_t)NQ * MROWS * MP;   // elems per bf16 M-matrix set

    // workspace layout (16B-aligned)
    float* S    = (float*)w;  w += sizeof(float) * (size_t)NQ * HW * NSL;   // 19.21 MB
    bf16*  Ts   = (bf16*)w;   w += sizeof(bf16)  * (size_t)NQ * RPQ * NSLP; // 10.32 MB
    bf16*  Tq   = (bf16*)w;   w += sizeof(bf16)  * (size_t)NQ * RPQ * NSLP; // 10.32 MB
    bf16*  qnbt = (bf16*)w;   w += sizeof(bf16)  * (size_t)NQ * RPQ * CC;   //  6.66 MB
    bf16*  snbt = (bf16*)w;   w += sizeof(bf16)  * (size_t)NSLP * CC;       //  1.27 MB
    float* R    = (float*)w;  w += sizeof(float) * (size_t)NQ * NWAY * HW;
    float* rhs  = (float*)w;  w += sizeof(float) * (size_t)NQ * HW;
    float* va   = (float*)w;  w += sizeof(float) * (size_t)NQ * HW;
    float* vb   = (float*)w;  w += sizeof(float) * (size_t)NQ * HW;
    float* Rtot = (float*)w;  w += sizeof(float) * (size_t)NQ * NWAY * HW;
    // S is dead after the softmaxes -> 6 bf16 M-matrices alias it (17.2 <= 19.2 MB)
    bf16* Mb   = (bf16*)S;
    bf16* MbT  = Mb   + MSZ;
    bf16* M2b  = MbT  + MSZ;
    bf16* M2bT = M2b  + MSZ;
    bf16* M4b  = M2bT + MSZ;
    bf16* M4bT = M4b  + MSZ;

    k_norm <<<dim3(13, NQ + NWAY), 256, 0, stream>>>(feat, qnbt, snbt);
    k_sgemm<<<dim3(16, 4, NQ), 64, 0, stream>>>(qnbt, snbt, S);
    k_ts   <<<NQ * HW, 256, 0, stream>>>(S, Ts, R);
    k_tq   <<<dim3(16, NQ), 256, 0, stream>>>(S, Tq);
    k_rhs  <<<NQ * HW, 256, 0, stream>>>(Tq, rhs);
    k_mgemm<<<dim3(4, 4, NQ), 64, 0, stream>>>(Tq, Ts, Mb, MbT);      // M
    k_msq  <<<dim3(4, 4, NQ), 64, 0, stream>>>(Mb, MbT, M2b, M2bT);   // M^2
    k_msq  <<<dim3(4, 4, NQ), 64, 0, stream>>>(M2b, M2bT, M4b, M4bT); // M^4
    k_rm   <<<dim3(4, NQ), 256, 0, stream>>>(MbT, R, Rtot);           // R(I+M)
    k_mv   <<<dim3(4, NQ), 256, 0, stream>>>(M4b, rhs, va);           // a=(I+M^4)rhs
    k_mv   <<<dim3(4, NQ), 256, 0, stream>>>(M2b, va, vb);            // b=(I+M^2)a
    k_out2 <<<NQ, 320, 0, stream>>>(Rtot, vb, out);
}

// Round 8
// 121.023 us; speedup vs baseline: 1.6981x; 1.6981x over previous
//
#include <hip/hip_runtime.h>
#include <math.h>

// Problem constants
#define NQ     25      // number of query images (= n_support)
#define NWAY   5
#define KSHOT  5
#define CC     640     // channels (k-dim of S gemm; 640 = 20*32)
#define HW     196     // 14*14
#define NSL    980     // NWAY*HW support locations
#define NSLP   992     // padded K for M-gemm (31*32)
#define RPQ    208     // padded row count per query (13*16)
#define BROWS  1024    // snbt allocated rows (8 n-tiles of 128)
#define MST    200     // M row stride in bf16 (400B, 16B-aligned; 25 bf16x8 chunks)
#define MRA    208     // M allocated rows per query
#define GAMMA  20.0f
#define GAMMA2 10.0f
#define NITER  8       // ||M||_1 = 0.25 -> tail 0.25^9/0.75 ~ 5e-6 vs threshold 1.77e-2

typedef __bf16 bf16;
typedef __attribute__((ext_vector_type(8))) __bf16 bf16x8;
typedef __attribute__((ext_vector_type(4))) float f32x4;

// ---------------------------------------------------------------------------
// K1: prototype mean + per-location L2 normalization -> TRANSPOSED bf16.
// qnbt[q][m][c] (rows padded to RPQ), snbt[j][c] (rows padded to BROWS).
// ---------------------------------------------------------------------------
__global__ __launch_bounds__(256) void k_norm(const float* __restrict__ feat,
                                              bf16* __restrict__ qnbt,
                                              bf16* __restrict__ snbt) {
    const int by = blockIdx.y;
    const int lx = threadIdx.x & 15;
    const int cg = threadIdx.x >> 4;
    const int l  = blockIdx.x * 16 + lx;
    const bool act = (l < HW);
    const int c0 = cg * 40;
    __shared__ float pr[16][17];

    float xv[40];
    float ss = 0.f;
    if (by < NQ) {
        const float* f = feat + (size_t)(NQ + by) * CC * HW;
#pragma unroll
        for (int i = 0; i < 40; ++i) {
            float x = act ? f[(c0 + i) * HW + l] : 0.f;
            xv[i] = x; ss += x * x;
        }
    } else {
        const int s = by - NQ;
        const float* f = feat + (size_t)(NQ + s * KSHOT) * CC * HW;
        const size_t img = (size_t)CC * HW;
#pragma unroll
        for (int i = 0; i < 40; ++i) {
            float m = 0.f;
            if (act) {
                const float* p = f + (c0 + i) * HW + l;
                m = 0.2f * (p[0] + p[img] + p[2 * img] + p[3 * img] + p[4 * img]);
            }
            xv[i] = m; ss += m * m;
        }
    }
    pr[cg][lx] = ss;
    __syncthreads();
    if (cg == 0) {
        float a = 0.f;
#pragma unroll
        for (int k = 0; k < 16; ++k) a += pr[k][lx];
        pr[0][lx] = 1.f / (1e-16f + sqrtf(a));
    }
    __syncthreads();
    const float inv = pr[0][lx];
    if (act) {
        bf16* o = (by < NQ) ? (qnbt + ((size_t)by * RPQ + l) * CC)
                            : (snbt + ((size_t)(by - NQ) * HW + l) * CC);
#pragma unroll
        for (int i = 0; i < 40; ++i) o[c0 + i] = (bf16)(xv[i] * inv);
    }
}

// ---------------------------------------------------------------------------
// K2: S[q][m][j] = sum_c qnbt[q][m][c] * snbt[j][c]  -- LDS-tiled MFMA GEMM.
// 128x128 tile, 256 threads = 4 waves (2x2), each wave 64x64 (4x4 of 16x16).
// m-tiles at rows {0, 80} (overlap region written twice, identical values).
// grid (8 n, 2 m, 25 q).
// ---------------------------------------------------------------------------
#define ASTR 40   // LDS row stride in bf16 (80B)
__global__ __launch_bounds__(256) void k_sgemm(const bf16* __restrict__ qnbt,
                                               const bf16* __restrict__ snbt,
                                               float* __restrict__ S) {
    const int q  = blockIdx.z;
    const int m0 = blockIdx.y * 80;          // {0, 80}: covers 0..207
    const int n0 = blockIdx.x * 128;         // 0..896: covers 0..1023 (alloc'd)
    __shared__ bf16 As[128 * ASTR];
    __shared__ bf16 Bs[128 * ASTR];
    const int t = threadIdx.x;
    const int lane = t & 63, w = t >> 6;
    const int wr = w >> 1, wc = w & 1;
    const int lo = lane & 15, hi = lane >> 4;
    const int sr = t >> 1, skc = (t & 1) * 16;   // stage: row, k-offset (2x bf16x8)

    const bf16* Aq = qnbt + (size_t)q * RPQ * CC;
    f32x4 acc[4][4] = {};

    for (int k0 = 0; k0 < CC; k0 += 32) {
        bf16x8 a0 = *reinterpret_cast<const bf16x8*>(&Aq[(size_t)(m0 + sr) * CC + k0 + skc]);
        bf16x8 a1 = *reinterpret_cast<const bf16x8*>(&Aq[(size_t)(m0 + sr) * CC + k0 + skc + 8]);
        bf16x8 b0 = *reinterpret_cast<const bf16x8*>(&snbt[(size_t)(n0 + sr) * CC + k0 + skc]);
        bf16x8 b1 = *reinterpret_cast<const bf16x8*>(&snbt[(size_t)(n0 + sr) * CC + k0 + skc + 8]);
        __syncthreads();   // previous step's frag reads done
        *reinterpret_cast<bf16x8*>(&As[sr * ASTR + skc])     = a0;
        *reinterpret_cast<bf16x8*>(&As[sr * ASTR + skc + 8]) = a1;
        *reinterpret_cast<bf16x8*>(&Bs[sr * ASTR + skc])     = b0;
        *reinterpret_cast<bf16x8*>(&Bs[sr * ASTR + skc + 8]) = b1;
        __syncthreads();
        bf16x8 af[4], bf[4];
#pragma unroll
        for (int mi = 0; mi < 4; ++mi)
            af[mi] = *reinterpret_cast<const bf16x8*>(&As[(wr * 64 + mi * 16 + lo) * ASTR + hi * 8]);
#pragma unroll
        for (int ni = 0; ni < 4; ++ni)
            bf[ni] = *reinterpret_cast<const bf16x8*>(&Bs[(wc * 64 + ni * 16 + lo) * ASTR + hi * 8]);
#pragma unroll
        for (int mi = 0; mi < 4; ++mi)
#pragma unroll
            for (int ni = 0; ni < 4; ++ni)
                acc[mi][ni] = __builtin_amdgcn_mfma_f32_16x16x32_bf16(af[mi], bf[ni], acc[mi][ni], 0, 0, 0);
    }

    float* Sq = S + (size_t)q * HW * NSL;
#pragma unroll
    for (int mi = 0; mi < 4; ++mi) {
#pragma unroll
        for (int ni = 0; ni < 4; ++ni) {
            const int j = n0 + wc * 64 + ni * 16 + lo;
            if (j >= NSL) continue;
#pragma unroll
            for (int r = 0; r < 4; ++r) {
                const int m = m0 + wr * 64 + mi * 16 + hi * 4 + r;
                if (m < HW) Sq[(size_t)m * NSL + j] = acc[mi][ni][r];
            }
        }
    }
}

// ---------------------------------------------------------------------------
// K3a: Ts row softmax -> bf16 (stride NSLP, K-pads 0) + fused class row-sums
//      R[q][s][m].  One block per (q,m) row.
// ---------------------------------------------------------------------------
__global__ __launch_bounds__(256) void k_ts(const float* __restrict__ S,
                                            bf16* __restrict__ Ts,
                                            float* __restrict__ R) {
    const int qm = blockIdx.x;
    const int q = qm / HW, m = qm - q * HW;
    const float* row = S + (size_t)qm * NSL;
    bf16* orow = Ts + ((size_t)q * RPQ + m) * NSLP;
    const int t = threadIdx.x, lane = t & 63, wv = t >> 6;
    __shared__ float redm[4], reds[4], rred[NWAY][4];
    float x[4];
    float mx = -1e30f;
#pragma unroll
    for (int p = 0; p < 4; ++p) {
        int j = t + p * 256;
        x[p] = (j < NSL) ? row[j] : -1e30f;
        mx = fmaxf(mx, x[p]);
    }
    for (int d = 32; d; d >>= 1) mx = fmaxf(mx, __shfl_xor(mx, d));
    if (lane == 0) redm[wv] = mx;
    __syncthreads();
    mx = fmaxf(fmaxf(redm[0], redm[1]), fmaxf(redm[2], redm[3]));
    float e[4], sum = 0.f;
#pragma unroll
    for (int p = 0; p < 4; ++p) {
        e[p] = expf(GAMMA * (x[p] - mx));
        sum += e[p];
    }
    for (int d = 32; d; d >>= 1) sum += __shfl_xor(sum, d);
    if (lane == 0) reds[wv] = sum;
    __syncthreads();
    const float inv = 1.f / (reds[0] + reds[1] + reds[2] + reds[3]);
    float racc[NWAY];
#pragma unroll
    for (int s = 0; s < NWAY; ++s) racc[s] = 0.f;
#pragma unroll
    for (int p = 0; p < 4; ++p) {
        int j = t + p * 256;
        if (j < NSL) {
            float val = e[p] * inv;
            orow[j] = (bf16)val;
            int cls = j / HW;
#pragma unroll
            for (int s = 0; s < NWAY; ++s) racc[s] += (cls == s) ? val : 0.f;
        } else if (j < NSLP) {
            orow[j] = (bf16)0.f;
        }
    }
#pragma unroll
    for (int s = 0; s < NWAY; ++s) {
        float a = racc[s];
        for (int d = 32; d; d >>= 1) a += __shfl_xor(a, d);
        if (lane == 0) rred[s][wv] = a;
    }
    __syncthreads();
    if (t < NWAY)
        R[((size_t)q * NWAY + t) * HW + m] =
            rred[t][0] + rred[t][1] + rred[t][2] + rred[t][3];
}

// ---------------------------------------------------------------------------
// K3b: Tq column softmax -> bf16, K-pads 0. grid (16, 25).
// ---------------------------------------------------------------------------
__global__ __launch_bounds__(256) void k_tq(const float* __restrict__ S,
                                            bf16* __restrict__ Tq) {
    const int q  = blockIdx.y;
    const int tx = threadIdx.x & 63;
    const int tg = threadIdx.x >> 6;
    const int j  = blockIdx.x * 64 + tx;
    const int m0 = tg * 49;
    const float* base = S + (size_t)q * HW * NSL;
    bf16* ob = Tq + (size_t)q * RPQ * NSLP;
    __shared__ float rmax[4][64], rsum[4][64];
    float xv[49];
    float mx = -1e30f;
    if (j < NSL) {
#pragma unroll
        for (int i = 0; i < 49; ++i) {
            xv[i] = base[(m0 + i) * NSL + j];
            mx = fmaxf(mx, xv[i]);
        }
    }
    rmax[tg][tx] = mx;
    __syncthreads();
    mx = fmaxf(fmaxf(rmax[0][tx], rmax[1][tx]), fmaxf(rmax[2][tx], rmax[3][tx]));
    float sum = 0.f;
    if (j < NSL) {
#pragma unroll
        for (int i = 0; i < 49; ++i) {
            xv[i] = expf(GAMMA2 * (xv[i] - mx));
            sum += xv[i];
        }
    }
    rsum[tg][tx] = sum;
    __syncthreads();
    const float inv = 1.f / (rsum[0][tx] + rsum[1][tx] + rsum[2][tx] + rsum[3][tx]);
    if (j < NSL) {
#pragma unroll
        for (int i = 0; i < 49; ++i) ob[(size_t)(m0 + i) * NSLP + j] = (bf16)(xv[i] * inv);
    } else if (j < NSLP) {
#pragma unroll
        for (int i = 0; i < 49; ++i) ob[(size_t)(m0 + i) * NSLP + j] = (bf16)0.f;
    }
}

// ---------------------------------------------------------------------------
// K4: M = 0.25 * Tq (196x992) * Ts^T (992x196) -> bf16, row stride MST=200,
// cols 196..199 zeroed, rows 196..207 zeroed. grid (4 j, 4 i, 25 q), 64 thr.
// ---------------------------------------------------------------------------
__global__ __launch_bounds__(64) void k_mgemm(const bf16* __restrict__ Tq,
                                              const bf16* __restrict__ Ts,
                                              bf16* __restrict__ Mb) {
    const int q  = blockIdx.z;
    const int it = blockIdx.y;
    const int jt = blockIdx.x;
    const int l  = threadIdx.x;
    const int lo = l & 15, hi = l >> 4;
    const bf16* Ap[4];
    const bf16* Bp[4];
#pragma unroll
    for (int mi = 0; mi < 4; ++mi)
        Ap[mi] = Tq + ((size_t)q * RPQ + it * 64 + mi * 16 + lo) * NSLP + hi * 8;
#pragma unroll
    for (int ni = 0; ni < 4; ++ni)
        Bp[ni] = Ts + ((size_t)q * RPQ + jt * 64 + ni * 16 + lo) * NSLP + hi * 8;

    f32x4 acc[4][4] = {};
#pragma unroll 2
    for (int k0 = 0; k0 < NSLP; k0 += 32) {
        bf16x8 a[4], b[4];
#pragma unroll
        for (int mi = 0; mi < 4; ++mi) a[mi] = *reinterpret_cast<const bf16x8*>(Ap[mi] + k0);
#pragma unroll
        for (int ni = 0; ni < 4; ++ni) b[ni] = *reinterpret_cast<const bf16x8*>(Bp[ni] + k0);
#pragma unroll
        for (int mi = 0; mi < 4; ++mi)
#pragma unroll
            for (int ni = 0; ni < 4; ++ni)
                acc[mi][ni] = __builtin_amdgcn_mfma_f32_16x16x32_bf16(a[mi], b[ni], acc[mi][ni], 0, 0, 0);
    }

    bf16* Mq = Mb + (size_t)q * MRA * MST;
#pragma unroll
    for (int mi = 0; mi < 4; ++mi) {
#pragma unroll
        for (int ni = 0; ni < 4; ++ni) {
            const int j = jt * 64 + ni * 16 + lo;
            if (j >= MST) continue;
#pragma unroll
            for (int r = 0; r < 4; ++r) {
                const int i = it * 64 + mi * 16 + hi * 4 + r;
                if (i >= MRA) continue;
                Mq[(size_t)i * MST + j] =
                    (i < HW && j < HW) ? (bf16)(0.25f * acc[mi][ni][r]) : (bf16)0.f;
            }
        }
    }
}

// ---------------------------------------------------------------------------
// K6: per-query Katz solve, 1024 threads (16 waves).
//   - M (bf16, 78.4 KB) -> LDS; rhs from Tq rowsums (16-wave parallel)
//   - NITER x (v <- rhs + M v): 4 col-quarters/row, LDS partial reduce
//   - out[q][s] = (R[s].v) / total
// ---------------------------------------------------------------------------
__global__ __launch_bounds__(1024) void k_solve2(const bf16* __restrict__ Mb,
                                                 const bf16* __restrict__ Tq,
                                                 const float* __restrict__ R,
                                                 float* __restrict__ out) {
    const int q = blockIdx.x;
    __shared__ __align__(16) bf16 Ms[HW * MST];            // 78,400 B
    __shared__ __align__(16) float va[MST], vb[MST];
    __shared__ float part[4][256];
    __shared__ float rhsl[HW];
    __shared__ float cls[NWAY];
    const int t = threadIdx.x, lane = t & 63, w = t >> 6;

    // --- M -> LDS (identical layout, contiguous bf16x8 copy) ---
    const bf16x8* gm = reinterpret_cast<const bf16x8*>(Mb + (size_t)q * MRA * MST);
    bf16x8* lm = reinterpret_cast<bf16x8*>(Ms);
    for (int i = t; i < HW * (MST / 8); i += 1024) lm[i] = gm[i];

    // --- rhs[m] = 1 + 0.5 * rowsum(Tq[q][m][:])  (K-pads are zero) ---
    for (int m = w; m < HW; m += 16) {
        const bf16x8* row = reinterpret_cast<const bf16x8*>(Tq + ((size_t)q * RPQ + m) * NSLP);
        float s = 0.f;
        for (int c = lane; c < NSLP / 8; c += 64) {
            bf16x8 v8 = row[c];
#pragma unroll
            for (int e = 0; e < 8; ++e) s += (float)v8[e];
        }
        for (int d = 32; d; d >>= 1) s += __shfl_xor(s, d);
        if (lane == 0) rhsl[m] = 1.f + 0.5f * s;
    }
    __syncthreads();
    if (t < MST) { va[t] = (t < HW) ? rhsl[t] : 0.f; vb[t] = 0.f; }
    __syncthreads();

    // --- iterations ---
    const int r = t & 255, qd = t >> 8;
    const int cstart = (qd == 0) ? 0 : 7 + 6 * (qd - 1);   // {0,7,13,19}
    const int ccnt   = (qd == 0) ? 7 : 6;                  // sum = 25 chunks (200 cols)
    for (int it = 0; it < NITER; ++it) {
        const float* src = (it & 1) ? vb : va;
        float* dst = (it & 1) ? va : vb;
        float a = 0.f;
        if (r < HW) {
            const bf16x8* mrow = reinterpret_cast<const bf16x8*>(&Ms[r * MST]);
            for (int c = cstart; c < cstart + ccnt; ++c) {
                bf16x8 mv = mrow[c];
                const float* sp = &src[c * 8];
#pragma unroll
                for (int e = 0; e < 8; ++e) a += (float)mv[e] * sp[e];
            }
        }
        part[qd][r] = a;
        __syncthreads();
        if (qd == 0 && r < HW)
            dst[r] = rhsl[r] + (part[0][r] + part[1][r] + part[2][r] + part[3][r]);
        __syncthreads();
    }
    // NITER even -> final v in va

    if (w < NWAY) {
        const float* Rs = R + ((size_t)q * NWAY + w) * HW;
        float a = 0.f;
        for (int m = lane; m < HW; m += 64) a += va[m] * Rs[m];
        for (int d = 32; d; d >>= 1) a += __shfl_xor(a, d);
        if (lane == 0) cls[w] = a;
    }
    __syncthreads();
    if (t == 0) {
        float tot = cls[0] + cls[1] + cls[2] + cls[3] + cls[4];
        float invt = 1.f / tot;
        for (int s = 0; s < NWAY; ++s) out[q * NWAY + s] = cls[s] * invt;
    }
}

// ---------------------------------------------------------------------------
extern "C" void kernel_launch(void* const* d_in, const int* in_sizes, int n_in,
                              void* d_out, int out_size, void* d_ws, size_t ws_size,
                              hipStream_t stream) {
    const float* feat = (const float*)d_in[0];
    float* out = (float*)d_out;
    char* w = (char*)d_ws;

    // workspace layout (16B-aligned)
    float* S    = (float*)w;  w += sizeof(float) * (size_t)NQ * HW * NSL;   // 19.21 MB
    bf16*  Ts   = (bf16*)w;   w += sizeof(bf16)  * (size_t)NQ * RPQ * NSLP; // 10.32 MB
    bf16*  Tq   = (bf16*)w;   w += sizeof(bf16)  * (size_t)NQ * RPQ * NSLP; // 10.32 MB
    bf16*  qnbt = (bf16*)w;   w += sizeof(bf16)  * (size_t)NQ * RPQ * CC;   //  6.66 MB
    bf16*  snbt = (bf16*)w;   w += sizeof(bf16)  * (size_t)BROWS * CC;      //  1.31 MB
    float* R    = (float*)w;  w += sizeof(float) * (size_t)NQ * NWAY * HW;
    // S is dead after both softmaxes -> bf16 M aliases it (2.08 MB <= 19.2 MB)
    bf16* Mb = (bf16*)S;

    k_norm  <<<dim3(13, NQ + NWAY), 256, 0, stream>>>(feat, qnbt, snbt);
    k_sgemm <<<dim3(8, 2, NQ), 256, 0, stream>>>(qnbt, snbt, S);
    k_ts    <<<NQ * HW, 256, 0, stream>>>(S, Ts, R);
    k_tq    <<<dim3(16, NQ), 256, 0, stream>>>(S, Tq);
    k_mgemm <<<dim3(4, 4, NQ), 64, 0, stream>>>(Tq, Ts, Mb);
    k_solve2<<<NQ, 1024, 0, stream>>>(Mb, Tq, R, out);
}